// Round 9
// baseline (528.560 us; speedup 1.0000x reference)
//
#include <hip/hip_runtime.h>
#include <hip/hip_fp16.h>
#include <math.h>

#define N_NODES 100000
#define N_EDGES 1600000
#define IN_F 256
#define OUT_F 128
#define SCAN_TPB 256
#define SCAN_EPB 1024

// gemm tiling
#define GM_ROWS 64            // rows per block
#define BK 32                 // K-tile (one 16x16x32 MFMA k-step)

typedef _Float16 h8 __attribute__((ext_vector_type(8)));
typedef float f4 __attribute__((ext_vector_type(4)));
// clang ext-vector types for __builtin_nontemporal_* (HIP_vector_type structs are rejected)
typedef int   i4v __attribute__((ext_vector_type(4)));
typedef float f4v __attribute__((ext_vector_type(4)));

// async global->LDS, 16B per lane; dest is wave-uniform base + lane*16 (linear)
#define GLD16(gp, lp) __builtin_amdgcn_global_load_lds( \
    (const __attribute__((address_space(1))) unsigned int*)(gp), \
    (__attribute__((address_space(3))) unsigned int*)(lp), 16, 0, 0)

// ---------------- zero degree counters (re-run safe: workspace persists) ----------------
__global__ __launch_bounds__(256) void zero_kernel(int4* __restrict__ deg_in4,
                                                   int4* __restrict__ deg_out4) {
    int i = blockIdx.x * 256 + threadIdx.x;
    if (i < N_NODES / 4) {
        deg_in4[i]  = make_int4(0, 0, 0, 0);
        deg_out4[i] = make_int4(0, 0, 0, 0);
    }
}

// ---------------- degree count via device-scope atomics ----------------
// 3.2M +1 atomics to 200k counters, random -> low contention, IC-side
// throughput well above this op count.
__global__ __launch_bounds__(256) void count_kernel(
        const int* __restrict__ src, const int* __restrict__ dst,
        int* __restrict__ deg_out, int* __restrict__ deg_in, int E) {
    int e0 = (blockIdx.x * 256 + threadIdx.x) * 4;
    if (e0 >= E) return;
    i4v s4 = __builtin_nontemporal_load((const i4v*)(src + e0));
    i4v d4 = __builtin_nontemporal_load((const i4v*)(dst + e0));
    #pragma unroll
    for (int j = 0; j < 4; ++j) {
        atomicAdd(&deg_out[s4[j]], 1);
        atomicAdd(&deg_in[d4[j]], 1);
    }
}

// ---------------- node pass: rs_out from deg_out + per-block deg_in sums ----------------
// block = 256 threads x 4 nodes = 1024 nodes (matches SCAN_EPB)
__global__ __launch_bounds__(256) void deg_pass_kernel(
        const int* __restrict__ deg_in, const int* __restrict__ deg_out,
        float* __restrict__ rs_out, int* __restrict__ spart, int N) {
    __shared__ int tmp[256];
    int t = threadIdx.x;
    int n0 = blockIdx.x * SCAN_EPB + t * 4;
    int s = 0;
    if (n0 < N) {
        int4 di = *(const int4*)(deg_in + n0);
        s = di.x + di.y + di.z + di.w;
        int4 dq = *(const int4*)(deg_out + n0);
        float4 rs;
        rs.x = rsqrtf((float)(dq.x < 1 ? 1 : dq.x));
        rs.y = rsqrtf((float)(dq.y < 1 ? 1 : dq.y));
        rs.z = rsqrtf((float)(dq.z < 1 ? 1 : dq.z));
        rs.w = rsqrtf((float)(dq.w < 1 ? 1 : dq.w));
        *(float4*)(rs_out + n0) = rs;
    }
    tmp[t] = s;
    __syncthreads();
    for (int off = 128; off > 0; off >>= 1) {
        if (t < off) tmp[t] += tmp[t + off];
        __syncthreads();
    }
    if (t == 0) spart[blockIdx.x] = tmp[0];
}

// ---------------- scan over block partials + final row_ptr + cursor ----------------
__global__ __launch_bounds__(128) void scan_part2(const int* __restrict__ partials,
                                                  int* __restrict__ bases, int nb) {
    __shared__ int tmp[128];
    int t = threadIdx.x;
    int v = (t < nb) ? partials[t] : 0;
    tmp[t] = v;
    __syncthreads();
    int x = v;
    for (int off = 1; off < 128; off <<= 1) {
        int y = (t >= off) ? tmp[t - off] : 0;
        __syncthreads();
        x += y;
        tmp[t] = x;
        __syncthreads();
    }
    if (t < nb) bases[t] = x - v;   // exclusive
}

__global__ __launch_bounds__(SCAN_TPB) void scan_part3(const int* __restrict__ deg,
                                                       const int* __restrict__ bases,
                                                       int* __restrict__ row_ptr,
                                                       int* __restrict__ cursor, int N) {
    __shared__ int tmp[SCAN_TPB];
    int t = threadIdx.x;
    int i0 = blockIdx.x * SCAN_EPB + t * 4;
    int v[4];
    int s = 0;
    #pragma unroll
    for (int j = 0; j < 4; ++j) { v[j] = (i0 + j < N) ? deg[i0 + j] : 0; s += v[j]; }
    tmp[t] = s;
    __syncthreads();
    int x = s;
    for (int off = 1; off < SCAN_TPB; off <<= 1) {
        int y = (t >= off) ? tmp[t - off] : 0;
        __syncthreads();
        x += y;
        tmp[t] = x;
        __syncthreads();
    }
    int excl = bases[blockIdx.x] + x - s;
    #pragma unroll
    for (int j = 0; j < 4; ++j) {
        if (i0 + j < N) { row_ptr[i0 + j] = excl; cursor[i0 + j] = excl; }
        excl += v[j];
    }
    if (blockIdx.x == gridDim.x - 1 && t == SCAN_TPB - 1) row_ptr[N] = bases[blockIdx.x] + x;
}

// ---------------- fill: dst-grouped packed (src, ew) via atomic row cursors ------------
// Slot within the row comes from atomicAdd(&cursor[dst],1) (order within a row
// is arbitrary; the per-dst float sum is order-insensitive at f16-rounding level).
__global__ __launch_bounds__(256) void fill_kernel(
        const int* __restrict__ src, const int* __restrict__ dst,
        const float* __restrict__ ew, int* __restrict__ cursor,
        int2* __restrict__ ed, int E) {
    int e0 = (blockIdx.x * 256 + threadIdx.x) * 4;
    if (e0 >= E) return;
    i4v s4 = __builtin_nontemporal_load((const i4v*)(src + e0));
    i4v d4 = __builtin_nontemporal_load((const i4v*)(dst + e0));
    f4v w4 = __builtin_nontemporal_load((const f4v*)(ew + e0));
    #pragma unroll
    for (int j = 0; j < 4; ++j) {
        int p = atomicAdd(&cursor[d4[j]], 1);
        unsigned long long v = (unsigned long long)(unsigned int)s4[j] |
                               ((unsigned long long)(unsigned int)__float_as_int(w4[j]) << 32);
        __builtin_nontemporal_store(v, (unsigned long long*)&ed[p]);
    }
}

// ---------------- Wt[n][k] = (f16) W[k][n] ----------------
__global__ void wt_kernel(const float* __restrict__ W, _Float16* __restrict__ Wt) {
    int i = blockIdx.x * blockDim.x + threadIdx.x;
    if (i < IN_F * OUT_F) {
        int n = i >> 8;
        int k = i & 255;
        Wt[i] = (_Float16)W[k * OUT_F + n];
    }
}

__device__ __forceinline__ float fast_tanh(float x) {
    // tanh(x) = 1 - 2/(e^2x + 1); exact at +/-inf, error << f16 quantization
    float e = __expf(2.0f * x);
    return 1.0f - 2.0f / (e + 1.0f);
}

// ---------------- h = tanh(rs[row] * (feat @ W)), f16 MFMA ----------------
// 2-phase async pipeline via global_load_lds (verified round 4: gemm dropped
// from ~100us off the top-5). Double-buffered A (swizzled) + B in 32 KB LDS,
// 4 blocks/CU.
__global__ __launch_bounds__(256, 4) void gemm_mfma_kernel(
        const float* __restrict__ feat, const _Float16* __restrict__ Wt,
        const float* __restrict__ rs_out, __half* __restrict__ h, int N) {
    __shared__ float    a_lds[2][GM_ROWS * BK];   // 2 x 8,192 B
    __shared__ _Float16 b_lds[2][OUT_F * BK];     // 2 x 8,192 B

    const int tid  = threadIdx.x;
    const int wave = tid >> 6;
    const int lane = tid & 63;
    const int m    = lane & 15;
    const int quad = lane >> 4;
    const int n0   = wave * 32;
    const int r0   = blockIdx.x * GM_ROWS;

    const int l3 = lane >> 3;
    const int ag = (lane & 7) ^ l3;
    int arow0 = r0 + 16 * wave + l3;      if (arow0 >= N) arow0 = N - 1;
    int arow1 = r0 + 16 * wave + 8 + l3;  if (arow1 >= N) arow1 = N - 1;
    const float* ga0 = feat + (size_t)arow0 * IN_F + ag * 4;
    const float* ga1 = feat + (size_t)arow1 * IN_F + ag * 4;
    const int brow0 = 32 * wave + (lane >> 2);
    const int brow1 = 32 * wave + 16 + (lane >> 2);
    const _Float16* gb0 = Wt + (size_t)brow0 * IN_F + (lane & 3) * 8;
    const _Float16* gb1 = Wt + (size_t)brow1 * IN_F + (lane & 3) * 8;

    f4 acc[4][2];
    #pragma unroll
    for (int t = 0; t < 4; ++t) {
        acc[t][0] = (f4){0.f, 0.f, 0.f, 0.f};
        acc[t][1] = (f4){0.f, 0.f, 0.f, 0.f};
    }

    // prologue: stage k-tile 0 into buf 0
    GLD16(ga0, &a_lds[0][(16 * wave) * BK]);
    GLD16(ga1, &a_lds[0][(16 * wave + 8) * BK]);
    GLD16(gb0, &b_lds[0][(32 * wave) * BK]);
    GLD16(gb1, &b_lds[0][(32 * wave + 16) * BK]);
    __syncthreads();

    #pragma unroll
    for (int kt = 0; kt < IN_F / BK; ++kt) {      // 8 k-tiles
        const int cb = kt & 1;
        if (kt < IN_F / BK - 1) {                 // stage next tile (async)
            const int nb2 = cb ^ 1;
            const int ko = (kt + 1) * BK;
            GLD16(ga0 + ko, &a_lds[nb2][(16 * wave) * BK]);
            GLD16(ga1 + ko, &a_lds[nb2][(16 * wave + 8) * BK]);
            GLD16(gb0 + ko, &b_lds[nb2][(32 * wave) * BK]);
            GLD16(gb1 + ko, &b_lds[nb2][(32 * wave + 16) * BK]);
            __builtin_amdgcn_sched_barrier(0);    // keep stages issued first
        }
        h8 b0 = *(const h8*)&b_lds[cb][(n0 + m) * BK + quad * 8];
        h8 b1 = *(const h8*)&b_lds[cb][(n0 + 16 + m) * BK + quad * 8];
        #pragma unroll
        for (int t = 0; t < 4; ++t) {
            const int ar = t * 16 + m;            // row in buffer; ar&7 == m&7
            float4 alo = *(const float4*)&a_lds[cb][ar * BK + (((quad * 2)     ^ (m & 7)) * 4)];
            float4 ahi = *(const float4*)&a_lds[cb][ar * BK + (((quad * 2 + 1) ^ (m & 7)) * 4)];
            h8 a;
            a[0] = (_Float16)alo.x; a[1] = (_Float16)alo.y;
            a[2] = (_Float16)alo.z; a[3] = (_Float16)alo.w;
            a[4] = (_Float16)ahi.x; a[5] = (_Float16)ahi.y;
            a[6] = (_Float16)ahi.z; a[7] = (_Float16)ahi.w;
            acc[t][0] = __builtin_amdgcn_mfma_f32_16x16x32_f16(a, b0, acc[t][0], 0, 0, 0);
            acc[t][1] = __builtin_amdgcn_mfma_f32_16x16x32_f16(a, b1, acc[t][1], 0, 0, 0);
        }
        __syncthreads();   // drains vmcnt(0): staged tile ready; all waves done with cb
    }

    #pragma unroll
    for (int t = 0; t < 4; ++t) {
        const int crow = r0 + t * 16 + quad * 4;
        float4 rs4 = *(const float4*)&rs_out[crow];   // rows contiguous, 16B-aligned
        const float rsv[4] = {rs4.x, rs4.y, rs4.z, rs4.w};
        #pragma unroll
        for (int r = 0; r < 4; ++r) {
            const int rr = crow + r;
            if (rr < N) {
                h[(size_t)rr * OUT_F + n0 + m]      = __float2half(fast_tanh(acc[t][0][r] * rsv[r]));
                h[(size_t)rr * OUT_F + n0 + 16 + m] = __float2half(fast_tanh(acc[t][1][r] * rsv[r]));
            }
        }
    }
}

// ---------------- gather: one wave per dst node, 4 edge-slots x 4-deep unroll ----------------
// Round-4 form (best measured: 85.6us). NT hints (r7) and 8-deep batching (r8)
// both measured worse -> gather is at the random-gather miss-service rate.
__global__ __launch_bounds__(256) void gather_kernel(
        const __half* __restrict__ h, const int2* __restrict__ ed,
        const int* __restrict__ row_ptr, float* __restrict__ out, int N) {
    int wave = threadIdx.x >> 6;
    int lane = threadIdx.x & 63;
    int node = blockIdx.x * 4 + wave;
    if (node >= N) return;
    int lo = row_ptr[node];
    int hi = row_ptr[node + 1];
    int p = lane >> 4;       // edge slot 0..3
    int c = lane & 15;       // feature octet: feats 8c..8c+7
    float acc[4][8];
    #pragma unroll
    for (int g = 0; g < 4; ++g)
        #pragma unroll
        for (int i = 0; i < 8; ++i) acc[g][i] = 0.f;

    for (int j = lo; j < hi; j += 16) {
        #pragma unroll
        for (int g = 0; g < 4; ++g) {
            int jj = j + g * 4 + p;
            int2 e = (jj < hi) ? ed[jj] : make_int2(0, 0);
            float w = __int_as_float(e.y);
            int4 rrow = *(const int4*)(h + (size_t)e.x * OUT_F + c * 8);
            float2 t;
            t = __half22float2(*(__half2*)&rrow.x); acc[g][0] += w * t.x; acc[g][1] += w * t.y;
            t = __half22float2(*(__half2*)&rrow.y); acc[g][2] += w * t.x; acc[g][3] += w * t.y;
            t = __half22float2(*(__half2*)&rrow.z); acc[g][4] += w * t.x; acc[g][5] += w * t.y;
            t = __half22float2(*(__half2*)&rrow.w); acc[g][6] += w * t.x; acc[g][7] += w * t.y;
        }
    }
    float v[8];
    #pragma unroll
    for (int i = 0; i < 8; ++i) {
        v[i] = (acc[0][i] + acc[1][i]) + (acc[2][i] + acc[3][i]);
        v[i] += __shfl_xor(v[i], 16);
        v[i] += __shfl_xor(v[i], 32);
    }
    if (p == 0) {
        int deg = hi - lo; if (deg < 1) deg = 1;
        float rs = rsqrtf((float)deg);
        float* op = out + (size_t)node * OUT_F + c * 8;
        *(float4*)op       = make_float4(v[0] * rs, v[1] * rs, v[2] * rs, v[3] * rs);
        *(float4*)(op + 4) = make_float4(v[4] * rs, v[5] * rs, v[6] * rs, v[7] * rs);
    }
}

extern "C" void kernel_launch(void* const* d_in, const int* in_sizes, int n_in,
                              void* d_out, int out_size, void* d_ws, size_t ws_size,
                              hipStream_t stream) {
    const float* feat   = (const float*)d_in[0];
    const float* weight = (const float*)d_in[1];
    const float* ew     = (const float*)d_in[2];
    const int*   src    = (const int*)d_in[3];
    const int*   dst    = (const int*)d_in[4];
    float* out = (float*)d_out;

    // workspace layout (atomic CSR build: hist/rank/partials/chunk_base removed)
    char* ws = (char*)d_ws;
    float* rs_out      = (float*)(ws);                       // 400,000
    int*   deg_in      = (int*)(ws + 400000);                // 400,000
    int*   row_ptr     = (int*)(ws + 800000);                // 400,016
    int*   spart       = (int*)(ws + 1200016);               // 512
    int*   sbases      = (int*)(ws + 1200528);               // 512
    int*   deg_out     = (int*)(ws + 1201056);               // 400,000
    int*   cursor      = (int*)(ws + 1601056);               // 400,000
    int2*  ed          = (int2*)(ws + 7601056);              // 12,800,000
    __half* h          = (__half*)(ws + 20401056);           // 25,600,000
    _Float16* Wt       = (_Float16*)(ws + 46001056);         // 65,536

    const int nb = (N_NODES + SCAN_EPB - 1) / SCAN_EPB;   // 98

    zero_kernel<<<(N_NODES / 4 + 255) / 256, 256, 0, stream>>>((int4*)deg_in, (int4*)deg_out);
    count_kernel<<<(N_EDGES / 4 + 255) / 256, 256, 0, stream>>>(src, dst, deg_out, deg_in, N_EDGES);
    deg_pass_kernel<<<nb, 256, 0, stream>>>(deg_in, deg_out, rs_out, spart, N_NODES);
    scan_part2<<<1, 128, 0, stream>>>(spart, sbases, nb);
    scan_part3<<<nb, SCAN_TPB, 0, stream>>>(deg_in, sbases, row_ptr, cursor, N_NODES);
    fill_kernel<<<(N_EDGES / 4 + 255) / 256, 256, 0, stream>>>(src, dst, ew, cursor, ed, N_EDGES);
    wt_kernel<<<(IN_F * OUT_F + 255) / 256, 256, 0, stream>>>(weight, Wt);
    gemm_mfma_kernel<<<(N_NODES + GM_ROWS - 1) / GM_ROWS, 256, 0, stream>>>(feat, Wt, rs_out, h, N_NODES);
    gather_kernel<<<(N_NODES + 3) / 4, 256, 0, stream>>>(h, ed, row_ptr, out, N_NODES);
}

// Round 10
// 372.656 us; speedup vs baseline: 1.4184x; 1.4184x over previous
//
#include <hip/hip_runtime.h>
#include <hip/hip_fp16.h>
#include <math.h>

#define N_NODES 100000
#define N_EDGES 1600000
#define IN_F 256
#define OUT_F 128
#define SCAN_EPB 512          // nodes per block in reduce/scan (2 per thread)

// hist partition: R node ranges x C edge chunks, packed 16-bit LDS bins
#define HR 4
#define HRANGE 25000          // nodes per range (50 KB LDS as packed u16)
#define HC 64
#define HCHUNK 25000          // edges per chunk (divisible by 4)
#define PWORDS (N_NODES / 2)  // packed words per chunk row (50,000)

// gemm tiling
#define GM_ROWS 64            // rows per block
#define BK 32                 // K-tile (one 16x16x32 MFMA k-step)

typedef _Float16 h8 __attribute__((ext_vector_type(8)));
typedef float f4 __attribute__((ext_vector_type(4)));
// clang ext-vector types for __builtin_nontemporal_* (HIP_vector_type structs are rejected)
typedef int   i4v __attribute__((ext_vector_type(4)));
typedef float f4v __attribute__((ext_vector_type(4)));

// async global->LDS, 16B per lane; dest is wave-uniform base + lane*16 (linear)
#define GLD16(gp, lp) __builtin_amdgcn_global_load_lds( \
    (const __attribute__((address_space(1))) unsigned int*)(gp), \
    (__attribute__((address_space(3))) unsigned int*)(lp), 16, 0, 0)

// ---------------- LDS-privatized histogram, packed 16-bit bins ----------------
// grid = HC x (2 type x HR) = 512 blocks. type 0: dst (+ per-edge rank),
// type 1: src. Counts per (chunk,node) < 25000 so 16-bit halves never overflow.
__global__ __launch_bounds__(256) void hist_kernel(
        const int* __restrict__ src, const int* __restrict__ dst,
        int* __restrict__ rank, unsigned int* __restrict__ partial_in,
        unsigned int* __restrict__ partial_out) {
    __shared__ unsigned int bins[HRANGE / 2];   // 50,000 B
    int b = blockIdx.x;
    int c = b >> 3;          // 0..63 chunk
    int tr = b & 7;
    int type = tr >> 2;      // 0 = dst, 1 = src
    int r = tr & 3;          // 0..3 range
    for (int i = threadIdx.x; i < HRANGE / 2; i += 256) bins[i] = 0;
    __syncthreads();
    const int* nodes = type ? src : dst;
    const int e0 = c * HCHUNK;
    const int lo = r * HRANGE;
    const int ngroups = HCHUNK / 4;   // 6250
    for (int g = threadIdx.x; g < ngroups; g += 256) {
        int e = e0 + g * 4;
        int4 n4 = *(const int4*)(nodes + e);
        int nn[4] = {n4.x, n4.y, n4.z, n4.w};
        #pragma unroll
        for (int j = 0; j < 4; ++j) {
            unsigned loc = (unsigned)(nn[j] - lo);
            if (loc < (unsigned)HRANGE) {
                unsigned sh = (loc & 1) * 16;
                unsigned old = atomicAdd(&bins[loc >> 1], 1u << sh);
                if (type == 0) rank[e + j] = (int)((old >> sh) & 0xffffu);
            }
        }
    }
    __syncthreads();
    unsigned int* part = type ? partial_out : partial_in;
    unsigned int* dstp = part + (size_t)c * PWORDS + (lo >> 1);
    for (int i = threadIdx.x; i < HRANGE / 2; i += 256) dstp[i] = bins[i];
}

// ---------------- fused reduce: deg_in + chunk_base16 + rs_out + scan partials ----------------
// 2 nodes/thread, 512 nodes/block -> grid 196 (was 98: 0.38 blocks/CU, 62% of
// the GPU idle on the most latency-exposed kernel of the chain).
__global__ __launch_bounds__(256) void fused_reduce_kernel(
        const unsigned int* __restrict__ partial_in,
        const unsigned int* __restrict__ partial_out,
        unsigned short* __restrict__ chunk_base16,
        int* __restrict__ deg_in, float* __restrict__ rs_out,
        int* __restrict__ spart, int N) {
    __shared__ int tmp[256];
    int t = threadIdx.x;
    int n0 = blockIdx.x * SCAN_EPB + t * 2;
    int run0 = 0, run1 = 0, so0 = 0, so1 = 0;
    if (n0 < N) {
        const int w0 = n0 >> 1;    // word offset (n0 even)
        #pragma unroll 4
        for (int c = 0; c < HC; ++c) {
            // chunk_base = running sum of per-chunk dst counts (2 x u16 packed)
            *(unsigned int*)(chunk_base16 + (size_t)c * N_NODES + n0) =
                (unsigned)(run0 & 0xffff) | ((unsigned)(run1 & 0xffff) << 16);
            unsigned pi = partial_in[(size_t)c * PWORDS + w0];
            run0 += (int)(pi & 0xffffu);  run1 += (int)(pi >> 16);
            unsigned po = partial_out[(size_t)c * PWORDS + w0];
            so0 += (int)(po & 0xffffu);   so1 += (int)(po >> 16);
        }
        *(int2*)(deg_in + n0) = make_int2(run0, run1);
        float2 rs;
        rs.x = rsqrtf((float)(so0 < 1 ? 1 : so0));
        rs.y = rsqrtf((float)(so1 < 1 ? 1 : so1));
        *(float2*)(rs_out + n0) = rs;
    }
    tmp[t] = run0 + run1;
    __syncthreads();
    for (int off = 128; off > 0; off >>= 1) {
        if (t < off) tmp[t] += tmp[t + off];
        __syncthreads();
    }
    if (t == 0) spart[blockIdx.x] = tmp[0];
}

// ---------------- merged scan: block-partials scan (redundant per block) + row_ptr ------
// Every block scans the nb(<=256)-entry spart array in LDS (~200 cy) -- removes
// the separate 1-block scan_part2 kernel and its dependency edge.
__global__ __launch_bounds__(256) void scan_kernel(const int* __restrict__ deg,
                                                   const int* __restrict__ spart,
                                                   int* __restrict__ row_ptr, int N, int nb) {
    __shared__ int sp[256];
    __shared__ int tmp[256];
    int t = threadIdx.x;
    // phase 1: inclusive scan of spart (all blocks, redundant)
    int pv = (t < nb) ? spart[t] : 0;
    sp[t] = pv;
    __syncthreads();
    int x = pv;
    for (int off = 1; off < 256; off <<= 1) {
        int y = (t >= off) ? sp[t - off] : 0;
        __syncthreads();
        x += y;
        sp[t] = x;
        __syncthreads();
    }
    const int base = (blockIdx.x == 0) ? 0 : sp[blockIdx.x - 1];
    if (blockIdx.x == 0 && t == 0) row_ptr[N] = sp[nb - 1];   // total = E
    // phase 2: per-block scan over 512 nodes (2 per thread)
    int i0 = blockIdx.x * SCAN_EPB + t * 2;
    int v0 = (i0 < N) ? deg[i0] : 0;
    int v1 = (i0 + 1 < N) ? deg[i0 + 1] : 0;
    int s = v0 + v1;
    tmp[t] = s;
    __syncthreads();
    int x2 = s;
    for (int off = 1; off < 256; off <<= 1) {
        int y = (t >= off) ? tmp[t - off] : 0;
        __syncthreads();
        x2 += y;
        tmp[t] = x2;
        __syncthreads();
    }
    int excl = base + x2 - s;
    if (i0 < N)     row_ptr[i0]     = excl;
    if (i0 + 1 < N) row_ptr[i0 + 1] = excl + v0;
}

// ---------------- atomic-free fill + folded W transpose ----------------
// Edge-order streams (src/dst/ew/rank) are read once -> nontemporal. First 128
// blocks additionally transpose W -> Wt (saves the separate wt launch).
__global__ __launch_bounds__(256) void fill_kernel(
        const int* __restrict__ src, const int* __restrict__ dst,
        const float* __restrict__ ew, const int* __restrict__ row_ptr,
        const unsigned short* __restrict__ chunk_base16,
        const int* __restrict__ rank, int2* __restrict__ ed,
        const float* __restrict__ W, _Float16* __restrict__ Wt, int E) {
    if (blockIdx.x < 128) {   // 128*256 == IN_F*OUT_F
        int i = blockIdx.x * 256 + threadIdx.x;
        int n = i >> 8;
        int k = i & 255;
        Wt[i] = (_Float16)W[k * OUT_F + n];
    }
    int e0 = (blockIdx.x * 256 + threadIdx.x) * 4;
    if (e0 >= E) return;
    i4v s4 = __builtin_nontemporal_load((const i4v*)(src + e0));
    i4v d4 = __builtin_nontemporal_load((const i4v*)(dst + e0));
    f4v w4 = __builtin_nontemporal_load((const f4v*)(ew + e0));
    i4v r4 = __builtin_nontemporal_load((const i4v*)(rank + e0));
    int c = e0 / HCHUNK;   // groups never straddle chunks (HCHUNK % 4 == 0)
    const unsigned short* cb = chunk_base16 + (size_t)c * N_NODES;
    #pragma unroll
    for (int j = 0; j < 4; ++j) {
        int d = d4[j];
        int p = row_ptr[d] + (int)cb[d] + r4[j];
        unsigned long long v = (unsigned long long)(unsigned int)s4[j] |
                               ((unsigned long long)(unsigned int)__float_as_int(w4[j]) << 32);
        __builtin_nontemporal_store(v, (unsigned long long*)&ed[p]);
    }
}

__device__ __forceinline__ float fast_tanh(float x) {
    // tanh(x) = 1 - 2/(e^2x + 1); exact at +/-inf, error << f16 quantization
    float e = __expf(2.0f * x);
    return 1.0f - 2.0f / (e + 1.0f);
}

// ---------------- h = tanh(rs[row] * (feat @ W)), f16 MFMA ----------------
// 2-phase async pipeline via global_load_lds (verified round 4: gemm dropped
// ~100us -> below top-5). Double-buffered A (swizzled) + B in 32 KB LDS,
// 4 blocks/CU.
__global__ __launch_bounds__(256, 4) void gemm_mfma_kernel(
        const float* __restrict__ feat, const _Float16* __restrict__ Wt,
        const float* __restrict__ rs_out, __half* __restrict__ h, int N) {
    __shared__ float    a_lds[2][GM_ROWS * BK];   // 2 x 8,192 B
    __shared__ _Float16 b_lds[2][OUT_F * BK];     // 2 x 8,192 B

    const int tid  = threadIdx.x;
    const int wave = tid >> 6;
    const int lane = tid & 63;
    const int m    = lane & 15;
    const int quad = lane >> 4;
    const int n0   = wave * 32;
    const int r0   = blockIdx.x * GM_ROWS;

    const int l3 = lane >> 3;
    const int ag = (lane & 7) ^ l3;
    int arow0 = r0 + 16 * wave + l3;      if (arow0 >= N) arow0 = N - 1;
    int arow1 = r0 + 16 * wave + 8 + l3;  if (arow1 >= N) arow1 = N - 1;
    const float* ga0 = feat + (size_t)arow0 * IN_F + ag * 4;
    const float* ga1 = feat + (size_t)arow1 * IN_F + ag * 4;
    const int brow0 = 32 * wave + (lane >> 2);
    const int brow1 = 32 * wave + 16 + (lane >> 2);
    const _Float16* gb0 = Wt + (size_t)brow0 * IN_F + (lane & 3) * 8;
    const _Float16* gb1 = Wt + (size_t)brow1 * IN_F + (lane & 3) * 8;

    f4 acc[4][2];
    #pragma unroll
    for (int t = 0; t < 4; ++t) {
        acc[t][0] = (f4){0.f, 0.f, 0.f, 0.f};
        acc[t][1] = (f4){0.f, 0.f, 0.f, 0.f};
    }

    // prologue: stage k-tile 0 into buf 0
    GLD16(ga0, &a_lds[0][(16 * wave) * BK]);
    GLD16(ga1, &a_lds[0][(16 * wave + 8) * BK]);
    GLD16(gb0, &b_lds[0][(32 * wave) * BK]);
    GLD16(gb1, &b_lds[0][(32 * wave + 16) * BK]);
    __syncthreads();

    #pragma unroll
    for (int kt = 0; kt < IN_F / BK; ++kt) {      // 8 k-tiles
        const int cb = kt & 1;
        if (kt < IN_F / BK - 1) {                 // stage next tile (async)
            const int nb2 = cb ^ 1;
            const int ko = (kt + 1) * BK;
            GLD16(ga0 + ko, &a_lds[nb2][(16 * wave) * BK]);
            GLD16(ga1 + ko, &a_lds[nb2][(16 * wave + 8) * BK]);
            GLD16(gb0 + ko, &b_lds[nb2][(32 * wave) * BK]);
            GLD16(gb1 + ko, &b_lds[nb2][(32 * wave + 16) * BK]);
            __builtin_amdgcn_sched_barrier(0);    // keep stages issued first
        }
        h8 b0 = *(const h8*)&b_lds[cb][(n0 + m) * BK + quad * 8];
        h8 b1 = *(const h8*)&b_lds[cb][(n0 + 16 + m) * BK + quad * 8];
        #pragma unroll
        for (int t = 0; t < 4; ++t) {
            const int ar = t * 16 + m;            // row in buffer; ar&7 == m&7
            float4 alo = *(const float4*)&a_lds[cb][ar * BK + (((quad * 2)     ^ (m & 7)) * 4)];
            float4 ahi = *(const float4*)&a_lds[cb][ar * BK + (((quad * 2 + 1) ^ (m & 7)) * 4)];
            h8 a;
            a[0] = (_Float16)alo.x; a[1] = (_Float16)alo.y;
            a[2] = (_Float16)alo.z; a[3] = (_Float16)alo.w;
            a[4] = (_Float16)ahi.x; a[5] = (_Float16)ahi.y;
            a[6] = (_Float16)ahi.z; a[7] = (_Float16)ahi.w;
            acc[t][0] = __builtin_amdgcn_mfma_f32_16x16x32_f16(a, b0, acc[t][0], 0, 0, 0);
            acc[t][1] = __builtin_amdgcn_mfma_f32_16x16x32_f16(a, b1, acc[t][1], 0, 0, 0);
        }
        __syncthreads();   // drains vmcnt(0): staged tile ready; all waves done with cb
    }

    #pragma unroll
    for (int t = 0; t < 4; ++t) {
        const int crow = r0 + t * 16 + quad * 4;
        float4 rs4 = *(const float4*)&rs_out[crow];   // rows contiguous, 16B-aligned
        const float rsv[4] = {rs4.x, rs4.y, rs4.z, rs4.w};
        #pragma unroll
        for (int r = 0; r < 4; ++r) {
            const int rr = crow + r;
            if (rr < N) {
                h[(size_t)rr * OUT_F + n0 + m]      = __float2half(fast_tanh(acc[t][0][r] * rsv[r]));
                h[(size_t)rr * OUT_F + n0 + 16 + m] = __float2half(fast_tanh(acc[t][1][r] * rsv[r]));
            }
        }
    }
}

// ---------------- gather: one wave per dst node, 4 edge-slots x 4-deep unroll ----------------
// Round-4 form (best measured: 85.6us). NT hints (r7: +1.2us), 8-deep batching
// (r8: +18us) and stream NT (r7: FETCH up) all measured worse -> this kernel is
// at the random-gather miss-service rate (~263 MB L2-fill at ~3.7 TB/s).
__global__ __launch_bounds__(256) void gather_kernel(
        const __half* __restrict__ h, const int2* __restrict__ ed,
        const int* __restrict__ row_ptr, float* __restrict__ out, int N) {
    int wave = threadIdx.x >> 6;
    int lane = threadIdx.x & 63;
    int node = blockIdx.x * 4 + wave;
    if (node >= N) return;
    int lo = row_ptr[node];
    int hi = row_ptr[node + 1];
    int p = lane >> 4;       // edge slot 0..3
    int c = lane & 15;       // feature octet: feats 8c..8c+7
    float acc[4][8];
    #pragma unroll
    for (int g = 0; g < 4; ++g)
        #pragma unroll
        for (int i = 0; i < 8; ++i) acc[g][i] = 0.f;

    for (int j = lo; j < hi; j += 16) {
        #pragma unroll
        for (int g = 0; g < 4; ++g) {
            int jj = j + g * 4 + p;
            int2 e = (jj < hi) ? ed[jj] : make_int2(0, 0);
            float w = __int_as_float(e.y);
            int4 rrow = *(const int4*)(h + (size_t)e.x * OUT_F + c * 8);
            float2 t;
            t = __half22float2(*(__half2*)&rrow.x); acc[g][0] += w * t.x; acc[g][1] += w * t.y;
            t = __half22float2(*(__half2*)&rrow.y); acc[g][2] += w * t.x; acc[g][3] += w * t.y;
            t = __half22float2(*(__half2*)&rrow.z); acc[g][4] += w * t.x; acc[g][5] += w * t.y;
            t = __half22float2(*(__half2*)&rrow.w); acc[g][6] += w * t.x; acc[g][7] += w * t.y;
        }
    }
    float v[8];
    #pragma unroll
    for (int i = 0; i < 8; ++i) {
        v[i] = (acc[0][i] + acc[1][i]) + (acc[2][i] + acc[3][i]);
        v[i] += __shfl_xor(v[i], 16);
        v[i] += __shfl_xor(v[i], 32);
    }
    if (p == 0) {
        int deg = hi - lo; if (deg < 1) deg = 1;
        float rs = rsqrtf((float)deg);
        float* op = out + (size_t)node * OUT_F + c * 8;
        *(float4*)op       = make_float4(v[0] * rs, v[1] * rs, v[2] * rs, v[3] * rs);
        *(float4*)(op + 4) = make_float4(v[4] * rs, v[5] * rs, v[6] * rs, v[7] * rs);
    }
}

extern "C" void kernel_launch(void* const* d_in, const int* in_sizes, int n_in,
                              void* d_out, int out_size, void* d_ws, size_t ws_size,
                              hipStream_t stream) {
    const float* feat   = (const float*)d_in[0];
    const float* weight = (const float*)d_in[1];
    const float* ew     = (const float*)d_in[2];
    const int*   src    = (const int*)d_in[3];
    const int*   dst    = (const int*)d_in[4];
    float* out = (float*)d_out;

    // workspace layout with aliasing (total 46.07 MB):
    //   ed (12.8M)  overlays partial_in  (dead after fused_reduce)
    //   h  (25.6M)  overlays chunk_base16 + partial_out (dead after fill/reduce)
    char* ws = (char*)d_ws;
    float* rs_out      = (float*)(ws);                       // 400,000
    int*   deg_in      = (int*)(ws + 400000);                // 400,000
    int*   row_ptr     = (int*)(ws + 800000);                // 400,016
    int*   spart       = (int*)(ws + 1200016);               // 784 (196 blocks)
    int*   rank        = (int*)(ws + 1201056);               // 6,400,000
    unsigned int* partial_in  = (unsigned int*)(ws + 7601056);   // 12,800,000
    int2*  ed          = (int2*)(ws + 7601056);                  // alias ^
    unsigned short* chunk_base16 = (unsigned short*)(ws + 20401056); // 12,800,000
    unsigned int* partial_out = (unsigned int*)(ws + 33201056);  // 12,800,000
    __half* h          = (__half*)(ws + 20401056);               // alias of cb16+p_out
    _Float16* Wt       = (_Float16*)(ws + 46001056);             // 65,536

    const int nb = (N_NODES + SCAN_EPB - 1) / SCAN_EPB;   // 196

    hist_kernel<<<2 * HR * HC, 256, 0, stream>>>(src, dst, rank, partial_in, partial_out);
    fused_reduce_kernel<<<nb, 256, 0, stream>>>(partial_in, partial_out, chunk_base16,
                                                deg_in, rs_out, spart, N_NODES);
    scan_kernel<<<nb, 256, 0, stream>>>(deg_in, spart, row_ptr, N_NODES, nb);
    fill_kernel<<<(N_EDGES / 4 + 255) / 256, 256, 0, stream>>>(src, dst, ew, row_ptr,
                                                               chunk_base16, rank, ed,
                                                               weight, Wt, N_EDGES);
    gemm_mfma_kernel<<<(N_NODES + GM_ROWS - 1) / GM_ROWS, 256, 0, stream>>>(feat, Wt, rs_out, h, N_NODES);
    gather_kernel<<<(N_NODES + 3) / 4, 256, 0, stream>>>(h, ed, row_ptr, out, N_NODES);
}